// Round 6
// baseline (297.609 us; speedup 1.0000x reference)
//
#include <hip/hip_runtime.h>
#include <hip/hip_bf16.h>
#include <math.h>

#define SLOPE 0.2f

typedef __attribute__((ext_vector_type(8))) short short8;
typedef __attribute__((ext_vector_type(4))) float f32x4;

static __device__ __forceinline__ float leakyf(float x) { return x >= 0.f ? x : SLOPE * x; }
static __device__ __forceinline__ float bflo(unsigned u) { return __builtin_bit_cast(float, u << 16); }
static __device__ __forceinline__ float bfhi(unsigned u) { return __builtin_bit_cast(float, u & 0xffff0000u); }
static __device__ __forceinline__ unsigned short f2bf(float f) {
    unsigned u = __builtin_bit_cast(unsigned, f);
    return (unsigned short)((u + 0x7fff + ((u >> 16) & 1)) >> 16);  // RNE
}

struct __align__(8) us4 { unsigned short a, b, c, d; };

// ---------------- fused weight transpose+convert -----------------------------------------
__global__ __launch_bounds__(256) void tconv_all(const float* __restrict__ W1,
                                                 const float* __restrict__ W2,
                                                 const float* __restrict__ W3,
                                                 const float* __restrict__ rW3,
                                                 unsigned short* __restrict__ W1t,
                                                 unsigned short* __restrict__ W2t,
                                                 unsigned short* __restrict__ W3c) {
    int i = blockIdx.x * 256 + threadIdx.x;
    const float* W; unsigned short* Wt; int K, lNc, idx;
    if (i < 32768)       { W = W1;  Wt = W1t;            K = 128; lNc = 8; idx = i; }
    else if (i < 98304)  { W = W2;  Wt = W2t;            K = 256; lNc = 8; idx = i - 32768; }
    else if (i < 114688) { W = W3;  Wt = W3c;            K = 256; lNc = 6; idx = i - 98304; }
    else                 { W = rW3; Wt = W3c + 64 * 256; K = 256; lNc = 6; idx = i - 114688; }
    int k = idx >> lNc, n = idx & ((1 << lNc) - 1);
    Wt[n * K + k] = f2bf(W[idx]);
}

// ---------------- MFMA GEMM (layers 1/2) + fused attention projections -------------------
template<bool A_F32>
__global__ __launch_bounds__(256) void gemm_l12(const void* __restrict__ Av,
                                                const unsigned short* __restrict__ Wt,
                                                unsigned short* __restrict__ outb,
                                                const float* __restrict__ al,
                                                const float* __restrict__ ar,
                                                float* __restrict__ el,
                                                float* __restrict__ er,
                                                int M, int K) {
    const int lane = threadIdx.x & 63;
    const int wid = threadIdx.x >> 6;       // head
    const int rlo = lane & 15;
    const int q = lane >> 4;
    const int kg = q * 8;
    const int m0 = blockIdx.x * 64;
    const int cbase = wid * 64;

    f32x4 acc[4][4];
#pragma unroll
    for (int mf = 0; mf < 4; ++mf)
#pragma unroll
        for (int nf = 0; nf < 4; ++nf) acc[mf][nf] = (f32x4){0.f, 0.f, 0.f, 0.f};

    for (int k0 = 0; k0 < K; k0 += 32) {
        short8 a[4];
#pragma unroll
        for (int mf = 0; mf < 4; ++mf) {
            int r = m0 + mf * 16 + rlo;
            if (r >= M) r = M - 1;  // clamp; affects only unstored rows
            if (A_F32) {
                const float* ap = (const float*)Av + (size_t)r * K + k0 + kg;
                float4 f0 = *(const float4*)ap;
                float4 f1 = *(const float4*)(ap + 4);
                short8 t;
                t[0] = f2bf(f0.x); t[1] = f2bf(f0.y); t[2] = f2bf(f0.z); t[3] = f2bf(f0.w);
                t[4] = f2bf(f1.x); t[5] = f2bf(f1.y); t[6] = f2bf(f1.z); t[7] = f2bf(f1.w);
                a[mf] = t;
            } else {
                a[mf] = *(const short8*)((const unsigned short*)Av + (size_t)r * K + k0 + kg);
            }
        }
#pragma unroll
        for (int nf = 0; nf < 4; ++nf) {
            short8 b = *(const short8*)(Wt + (size_t)(cbase + nf * 16 + rlo) * K + k0 + kg);
#pragma unroll
            for (int mf = 0; mf < 4; ++mf)
                acc[mf][nf] = __builtin_amdgcn_mfma_f32_16x16x32_bf16(a[mf], b, acc[mf][nf], 0, 0, 0);
        }
    }

    float alv[4], arv[4];
#pragma unroll
    for (int nf = 0; nf < 4; ++nf) {
        alv[nf] = al[cbase + nf * 16 + rlo];
        arv[nf] = ar[cbase + nf * 16 + rlo];
    }

#pragma unroll
    for (int mf = 0; mf < 4; ++mf) {
#pragma unroll
        for (int reg = 0; reg < 4; ++reg) {
            int r = m0 + mf * 16 + q * 4 + reg;
            float pl = 0.f, pr = 0.f;
#pragma unroll
            for (int nf = 0; nf < 4; ++nf) {
                pl += acc[mf][nf][reg] * alv[nf];
                pr += acc[mf][nf][reg] * arv[nf];
            }
#pragma unroll
            for (int off = 1; off < 16; off <<= 1) {
                pl += __shfl_xor(pl, off);
                pr += __shfl_xor(pr, off);
            }
            if (rlo == 0 && r < M) {
                el[(size_t)r * 4 + wid] = pl;
                er[(size_t)r * 4 + wid] = pr;
            }
            if (r < M) {
#pragma unroll
                for (int nf = 0; nf < 4; ++nf)
                    outb[(size_t)r * 256 + cbase + nf * 16 + rlo] = f2bf(acc[mf][nf][reg]);
            }
        }
    }
}

// ---------------- layer-3 fused GEMM: h2 @ [W3 | res_W3] ---------------------------------
__global__ __launch_bounds__(256) void gemm_l3(const unsigned short* __restrict__ A,
                                               const unsigned short* __restrict__ Wt,
                                               unsigned short* __restrict__ featb,
                                               float* __restrict__ resf,
                                               const float* __restrict__ al,
                                               const float* __restrict__ ar,
                                               float* __restrict__ el,
                                               float* __restrict__ er, int M) {
    const int K = 256;
    const int lane = threadIdx.x & 63;
    const int wid = threadIdx.x >> 6;
    const int rlo = lane & 15;
    const int q = lane >> 4;
    const int kg = q * 8;
    const int m0 = blockIdx.x * 128 + (wid >> 1) * 64;
    const int ch = wid & 1;
    const int cbase = ch * 64;

    f32x4 acc[4][4];
#pragma unroll
    for (int mf = 0; mf < 4; ++mf)
#pragma unroll
        for (int nf = 0; nf < 4; ++nf) acc[mf][nf] = (f32x4){0.f, 0.f, 0.f, 0.f};

    for (int k0 = 0; k0 < K; k0 += 32) {
        short8 a[4];
#pragma unroll
        for (int mf = 0; mf < 4; ++mf) {
            int r = m0 + mf * 16 + rlo;
            if (r >= M) r = M - 1;
            a[mf] = *(const short8*)(A + (size_t)r * K + k0 + kg);
        }
#pragma unroll
        for (int nf = 0; nf < 4; ++nf) {
            short8 b = *(const short8*)(Wt + (size_t)(cbase + nf * 16 + rlo) * K + k0 + kg);
#pragma unroll
            for (int mf = 0; mf < 4; ++mf)
                acc[mf][nf] = __builtin_amdgcn_mfma_f32_16x16x32_bf16(a[mf], b, acc[mf][nf], 0, 0, 0);
        }
    }

    float alv[4], arv[4];
    if (ch == 0) {
#pragma unroll
        for (int nf = 0; nf < 4; ++nf) {
            alv[nf] = al[nf * 16 + rlo];
            arv[nf] = ar[nf * 16 + rlo];
        }
    }

#pragma unroll
    for (int mf = 0; mf < 4; ++mf) {
#pragma unroll
        for (int reg = 0; reg < 4; ++reg) {
            int r = m0 + mf * 16 + q * 4 + reg;
            if (ch == 0) {
                float pl = 0.f, pr = 0.f;
#pragma unroll
                for (int nf = 0; nf < 4; ++nf) {
                    pl += acc[mf][nf][reg] * alv[nf];
                    pr += acc[mf][nf][reg] * arv[nf];
                }
#pragma unroll
                for (int off = 1; off < 16; off <<= 1) {
                    pl += __shfl_xor(pl, off);
                    pr += __shfl_xor(pr, off);
                }
                if (rlo == 0 && r < M) { el[r] = pl; er[r] = pr; }
                if (r < M) {
#pragma unroll
                    for (int nf = 0; nf < 4; ++nf)
                        featb[(size_t)r * 64 + nf * 16 + rlo] = f2bf(acc[mf][nf][reg]);
                }
            } else if (r < M) {
#pragma unroll
                for (int nf = 0; nf < 4; ++nf)
                    resf[(size_t)r * 64 + nf * 16 + rlo] = acc[mf][nf][reg];
            }
        }
    }
}

// ---------------- CSR build --------------------------------------------------------------
__global__ void hist_kernel(const int* __restrict__ dst, int* __restrict__ counts, int e) {
    int i = blockIdx.x * blockDim.x + threadIdx.x;
    if (i < e) atomicAdd(&counts[dst[i]], 1);
}

__global__ __launch_bounds__(1024) void scan_block(const int* __restrict__ counts,
                                                   int* __restrict__ offsets,
                                                   int* __restrict__ bsums, int n) {
    __shared__ int ws[16];
    int tid = threadIdx.x, lane = tid & 63, wid = tid >> 6;
    int idx = blockIdx.x * 1024 + tid;
    int v = (idx < n) ? counts[idx] : 0;
    int s = v;
#pragma unroll
    for (int off = 1; off < 64; off <<= 1) {
        int t = __shfl_up(s, off);
        if (lane >= off) s += t;
    }
    if (lane == 63) ws[wid] = s;
    __syncthreads();
    if (tid < 16) {
        int w2 = ws[tid];
#pragma unroll
        for (int off = 1; off < 16; off <<= 1) {
            int t = __shfl_up(w2, off);
            if (tid >= off) w2 += t;
        }
        ws[tid] = w2;
    }
    __syncthreads();
    int wpre = wid ? ws[wid - 1] : 0;
    if (idx < n) offsets[idx] = wpre + s - v;
    if (tid == 0) bsums[blockIdx.x] = ws[15];
}

__global__ __launch_bounds__(1024) void add_off(const int* __restrict__ bsums,
                                                int* __restrict__ offsets,
                                                int* __restrict__ cursor, int n, int e, int nb) {
    __shared__ int base_s;
    int tid = threadIdx.x;
    if (tid < 64) {
        int v = (tid < blockIdx.x && tid < nb) ? bsums[tid] : 0;
#pragma unroll
        for (int off = 32; off > 0; off >>= 1) v += __shfl_xor(v, off);
        if (tid == 0) base_s = v;
    }
    __syncthreads();
    int idx = blockIdx.x * 1024 + tid;
    if (idx < n) {
        int v = offsets[idx] + base_s;
        offsets[idx] = v;
        cursor[idx] = v;
    }
    if (idx == 0) offsets[n] = e;
}

__global__ void scatter_kernel(const int* __restrict__ src, const int* __restrict__ dst,
                               int* __restrict__ cursor, int* __restrict__ csr_src,
                               int* __restrict__ csr_dst, int e) {
    int i = blockIdx.x * blockDim.x + threadIdx.x;
    if (i < e) {
        int d = dst[i];
        int pos = atomicAdd(&cursor[d], 1);
        csr_src[pos] = src[i];
        csr_dst[pos] = d;
    }
}

// ---------------- edge-parallel score precompute -----------------------------------------
// w[e][h] = exp(min(leaky(el[src_e][h] + er[dst_e][h]), 80)), CSR edge order.
template<int H>
__global__ __launch_bounds__(256) void edge_scores(const int* __restrict__ csr_src,
                                                   const int* __restrict__ csr_dst,
                                                   const float* __restrict__ el,
                                                   const float* __restrict__ er,
                                                   float* __restrict__ w, int E) {
    int e = blockIdx.x * 256 + threadIdx.x;
    if (e >= E) return;
    int s = csr_src[e], d = csr_dst[e];
    if (H == 4) {
        float4 l = *(const float4*)(el + (size_t)s * 4);
        float4 r = *(const float4*)(er + (size_t)d * 4);
        float4 o;
        o.x = __expf(fminf(leakyf(l.x + r.x), 80.f));
        o.y = __expf(fminf(leakyf(l.y + r.y), 80.f));
        o.z = __expf(fminf(leakyf(l.z + r.z), 80.f));
        o.w = __expf(fminf(leakyf(l.w + r.w), 80.f));
        *(float4*)(w + (size_t)e * 4) = o;
    } else {
        w[e] = __expf(fminf(leakyf(el[s] + er[d]), 80.f));
    }
}

// ---------------- aggregate: pure gather + FMA, 8-wide masked unroll ---------------------
// one wave per node. H==4: lane owns feats [lane*4,+4), head=lane>>4. H==1: lane owns feat lane.
// RES: 0 none, 1 bf16 resid, 2 f32 resid. ACT: 0 none, 1 elu.
template<int H, int RES, int ACT, bool OUT_BF16>
__global__ __launch_bounds__(256) void gat_agg(const unsigned short* __restrict__ fp,
                                               const float* __restrict__ wbuf,
                                               const int* __restrict__ offsets,
                                               const int* __restrict__ csr_src,
                                               const void* __restrict__ resid,
                                               void* __restrict__ outv, int n) {
    const int D = H * 64;
    int node = blockIdx.x * 4 + (threadIdx.x >> 6);
    int lane = threadIdx.x & 63;
    if (node >= n) return;
    int e0 = offsets[node], e1 = offsets[node + 1];
    const int hf = (H == 4) ? (lane >> 4) : 0;

    float den = 0.f;
    float acc[4] = {0.f, 0.f, 0.f, 0.f};

    for (int e = e0; e < e1; e += 8) {
        int s[8];
        float w[8];
#pragma unroll
        for (int j = 0; j < 8; ++j) {
            int idx = e + j;
            bool ok = idx < e1;
            int ii = ok ? idx : (e1 - 1);
            s[j] = csr_src[ii];
            float wv = (H == 4) ? wbuf[(size_t)ii * 4 + hf] : wbuf[ii];
            w[j] = ok ? wv : 0.f;
        }
        if (H == 4) {
            uint2 u[8];
#pragma unroll
            for (int j = 0; j < 8; ++j)
                u[j] = *(const uint2*)(fp + (size_t)s[j] * 256 + lane * 4);
#pragma unroll
            for (int j = 0; j < 8; ++j) {
                den += w[j];
                acc[0] += w[j] * bflo(u[j].x);
                acc[1] += w[j] * bfhi(u[j].x);
                acc[2] += w[j] * bflo(u[j].y);
                acc[3] += w[j] * bfhi(u[j].y);
            }
        } else {
            unsigned u[8];
#pragma unroll
            for (int j = 0; j < 8; ++j)
                u[j] = ((const unsigned short*)fp)[(size_t)s[j] * 64 + lane];
#pragma unroll
            for (int j = 0; j < 8; ++j) {
                den += w[j];
                acc[0] += w[j] * bflo(u[j]);
            }
        }
    }

    float inv = den > 0.f ? 1.f / den : 0.f;
    float v[4];
#pragma unroll
    for (int i = 0; i < 4; ++i) v[i] = acc[i] * inv;

    if (RES == 1) {
        uint2 ru = *(const uint2*)((const unsigned short*)resid + (size_t)node * D + lane * 4);
        v[0] += bflo(ru.x); v[1] += bfhi(ru.x); v[2] += bflo(ru.y); v[3] += bfhi(ru.y);
    } else if (RES == 2) {
        v[0] += ((const float*)resid)[(size_t)node * D + lane];
    }
    if (ACT == 1) {
#pragma unroll
        for (int i = 0; i < 4; ++i) v[i] = v[i] > 0.f ? v[i] : __expf(v[i]) - 1.f;
    }
    if (OUT_BF16) {
        if (H == 4) {
            us4 o = {f2bf(v[0]), f2bf(v[1]), f2bf(v[2]), f2bf(v[3])};
            *(us4*)((unsigned short*)outv + (size_t)node * D + lane * 4) = o;
        } else {
            ((unsigned short*)outv)[(size_t)node * D + lane] = f2bf(v[0]);
        }
    } else {
        if (H == 4) {
            float4 o = {v[0], v[1], v[2], v[3]};
            *(float4*)((float*)outv + (size_t)node * D + lane * 4) = o;
        } else {
            ((float*)outv)[(size_t)node * D + lane] = v[0];
        }
    }
}

// ---------------- launcher ----------------------------------------------------------------
extern "C" void kernel_launch(void* const* d_in, const int* in_sizes, int n_in,
                              void* d_out, int out_size, void* d_ws, size_t ws_size,
                              hipStream_t stream) {
    const float* x      = (const float*)d_in[0];
    const float* W1     = (const float*)d_in[1];
    const float* al1    = (const float*)d_in[2];
    const float* ar1    = (const float*)d_in[3];
    const float* W2     = (const float*)d_in[4];
    const float* al2    = (const float*)d_in[5];
    const float* ar2    = (const float*)d_in[6];
    const float* W3     = (const float*)d_in[7];
    const float* al3    = (const float*)d_in[8];
    const float* ar3    = (const float*)d_in[9];
    const float* res_W3 = (const float*)d_in[10];
    const int*   src    = (const int*)d_in[11];
    const int*   dst    = (const int*)d_in[12];

    const int N = in_sizes[0] / 128;    // 50000
    const int E = in_sizes[11];         // 500000

    float* out = (float*)d_out;

    // workspace layout
    unsigned short* featb = (unsigned short*)d_ws;          // [N,256] (layer3: [N,64])
    unsigned short* h1    = featb + (size_t)N * 256;        // [N,256]
    unsigned short* h2    = h1 + (size_t)N * 256;           // [N,256]
    unsigned short* W1t   = h2 + (size_t)N * 256;           // [256,128]
    unsigned short* W2t   = W1t + 256 * 128;                // [256,256]
    unsigned short* W3c   = W2t + 256 * 256;                // [128,256] = [W3t | RW3t]
    float* resf = (float*)(W3c + 128 * 256);                // [N,64]
    float* el   = resf + (size_t)N * 64;                    // [N,4]
    float* er   = el + (size_t)N * 4;                       // [N,4]
    float* wbuf = er + (size_t)N * 4;                       // [E,4]
    int* offsets = (int*)(wbuf + (size_t)E * 4);            // [N+1]
    int* cursor  = offsets + (N + 1);                       // [N]
    int* csr_src = cursor + N;                              // [E]
    int* csr_dst = csr_src + E;                             // [E]
    int* bsums   = csr_dst + E;                             // [64]

    const int T = 256;
    const int scan_blocks = (N + 1023) / 1024;  // 49 (<= 64 for add_off)
    const int edge_blocks = (E + T - 1) / T;

    // ---- weight conversions (fused) ----
    tconv_all<<<512, T, 0, stream>>>(W1, W2, W3, res_W3, W1t, W2t, W3c);

    // ---- CSR by dst ----
    hipMemsetAsync(cursor, 0, (size_t)N * sizeof(int), stream);
    hist_kernel<<<edge_blocks, T, 0, stream>>>(dst, cursor, E);
    scan_block<<<scan_blocks, 1024, 0, stream>>>(cursor, offsets, bsums, N);
    add_off<<<scan_blocks, 1024, 0, stream>>>(bsums, offsets, cursor, N, E, scan_blocks);
    scatter_kernel<<<edge_blocks, T, 0, stream>>>(src, dst, cursor, csr_src, csr_dst, E);

    int gemm12_blocks = (N + 63) / 64;
    int gemm3_blocks = (N + 127) / 128;
    int node_blocks = (N + 3) / 4;

    // ---- Layer 1 ----
    gemm_l12<true><<<gemm12_blocks, T, 0, stream>>>(x, W1t, featb, al1, ar1, el, er, N, 128);
    edge_scores<4><<<edge_blocks, T, 0, stream>>>(csr_src, csr_dst, el, er, wbuf, E);
    gat_agg<4, 0, 1, true><<<node_blocks, T, 0, stream>>>(featb, wbuf, offsets, csr_src, nullptr, h1, N);

    // ---- Layer 2 ----
    gemm_l12<false><<<gemm12_blocks, T, 0, stream>>>(h1, W2t, featb, al2, ar2, el, er, N, 256);
    edge_scores<4><<<edge_blocks, T, 0, stream>>>(csr_src, csr_dst, el, er, wbuf, E);
    gat_agg<4, 1, 1, true><<<node_blocks, T, 0, stream>>>(featb, wbuf, offsets, csr_src, h1, h2, N);

    // ---- Layer 3 ----
    gemm_l3<<<gemm3_blocks, T, 0, stream>>>(h2, W3c, featb, resf, al3, ar3, el, er, N);
    edge_scores<1><<<edge_blocks, T, 0, stream>>>(csr_src, csr_dst, el, er, wbuf, E);
    gat_agg<1, 2, 0, false><<<node_blocks, T, 0, stream>>>(featb, wbuf, offsets, csr_src, resf, out, N);
}

// Round 7
// 287.939 us; speedup vs baseline: 1.0336x; 1.0336x over previous
//
#include <hip/hip_runtime.h>
#include <hip/hip_bf16.h>
#include <math.h>

#define SLOPE 0.2f

typedef __attribute__((ext_vector_type(8))) short short8;
typedef __attribute__((ext_vector_type(4))) float f32x4;
typedef __attribute__((ext_vector_type(4))) int   i32x4;

static __device__ __forceinline__ float leakyf(float x) { return x >= 0.f ? x : SLOPE * x; }
static __device__ __forceinline__ float bflo(unsigned u) { return __builtin_bit_cast(float, u << 16); }
static __device__ __forceinline__ float bfhi(unsigned u) { return __builtin_bit_cast(float, u & 0xffff0000u); }
static __device__ __forceinline__ unsigned short f2bf(float f) {
    unsigned u = __builtin_bit_cast(unsigned, f);
    return (unsigned short)((u + 0x7fff + ((u >> 16) & 1)) >> 16);  // RNE
}

struct __align__(8) us4 { unsigned short a, b, c, d; };

// Permuted within-head column layout: slot p (in [0,64) of a head block) holds true
// column c64(p) = (p&3)*16 + (p>>2).  Inverse: p(c) = (c&15)*4 + (c>>4).
// All [N,256]/[N,64] intermediates use this layout; weights' K-rows are pre-permuted.

// ---------------- fused weight transpose+convert+K-permute -------------------------------
__global__ __launch_bounds__(256) void tconv_all(const float* __restrict__ W1,
                                                 const float* __restrict__ W2,
                                                 const float* __restrict__ W3,
                                                 const float* __restrict__ rW3,
                                                 unsigned short* __restrict__ W1t,
                                                 unsigned short* __restrict__ W2t,
                                                 unsigned short* __restrict__ W3c) {
    int i = blockIdx.x * 256 + threadIdx.x;
    const float* W; unsigned short* Wt; int K, lNc, idx; bool permK;
    if (i < 32768)       { W = W1;  Wt = W1t;            K = 128; lNc = 8; idx = i;          permK = false; }
    else if (i < 98304)  { W = W2;  Wt = W2t;            K = 256; lNc = 8; idx = i - 32768;  permK = true; }
    else if (i < 114688) { W = W3;  Wt = W3c;            K = 256; lNc = 6; idx = i - 98304;  permK = true; }
    else                 { W = rW3; Wt = W3c + 64 * 256; K = 256; lNc = 6; idx = i - 114688; permK = true; }
    int k = idx >> lNc, n = idx & ((1 << lNc) - 1);
    int kp = permK ? ((k & ~63) | (((k & 15) << 2) | ((k & 63) >> 4))) : k;
    Wt[n * K + kp] = f2bf(W[idx]);
}

// ---------------- MFMA GEMM (layers 1/2) + fused attention projections -------------------
// A_F32: A is f32 true-order (layer 1 input); else bf16 permuted (K-rows of Wt permuted).
// Output stored in permuted layout (us4 coalesced stores). el/er computed on true cols.
template<bool A_F32>
__global__ __launch_bounds__(256) void gemm_l12(const void* __restrict__ Av,
                                                const unsigned short* __restrict__ Wt,
                                                unsigned short* __restrict__ outb,
                                                const float* __restrict__ al,
                                                const float* __restrict__ ar,
                                                float* __restrict__ el,
                                                float* __restrict__ er,
                                                int M, int K) {
    const int lane = threadIdx.x & 63;
    const int wid = threadIdx.x >> 6;       // head
    const int rlo = lane & 15;
    const int q = lane >> 4;
    const int kg = q * 8;
    const int m0 = blockIdx.x * 64;
    const int cbase = wid * 64;

    f32x4 acc[4][4];
#pragma unroll
    for (int mf = 0; mf < 4; ++mf)
#pragma unroll
        for (int nf = 0; nf < 4; ++nf) acc[mf][nf] = (f32x4){0.f, 0.f, 0.f, 0.f};

    for (int k0 = 0; k0 < K; k0 += 32) {
        short8 a[4];
#pragma unroll
        for (int mf = 0; mf < 4; ++mf) {
            int r = m0 + mf * 16 + rlo;
            if (r >= M) r = M - 1;  // clamp; affects only unstored rows
            if (A_F32) {
                const float* ap = (const float*)Av + (size_t)r * K + k0 + kg;
                float4 f0 = *(const float4*)ap;
                float4 f1 = *(const float4*)(ap + 4);
                short8 t;
                t[0] = f2bf(f0.x); t[1] = f2bf(f0.y); t[2] = f2bf(f0.z); t[3] = f2bf(f0.w);
                t[4] = f2bf(f1.x); t[5] = f2bf(f1.y); t[6] = f2bf(f1.z); t[7] = f2bf(f1.w);
                a[mf] = t;
            } else {
                a[mf] = *(const short8*)((const unsigned short*)Av + (size_t)r * K + k0 + kg);
            }
        }
#pragma unroll
        for (int nf = 0; nf < 4; ++nf) {
            short8 b = *(const short8*)(Wt + (size_t)(cbase + nf * 16 + rlo) * K + k0 + kg);
#pragma unroll
            for (int mf = 0; mf < 4; ++mf)
                acc[mf][nf] = __builtin_amdgcn_mfma_f32_16x16x32_bf16(a[mf], b, acc[mf][nf], 0, 0, 0);
        }
    }

    float alv[4], arv[4];
#pragma unroll
    for (int nf = 0; nf < 4; ++nf) {
        alv[nf] = al[cbase + nf * 16 + rlo];
        arv[nf] = ar[cbase + nf * 16 + rlo];
    }

#pragma unroll
    for (int mf = 0; mf < 4; ++mf) {
#pragma unroll
        for (int reg = 0; reg < 4; ++reg) {
            int r = m0 + mf * 16 + q * 4 + reg;
            float pl = 0.f, pr = 0.f;
#pragma unroll
            for (int nf = 0; nf < 4; ++nf) {
                pl += acc[mf][nf][reg] * alv[nf];
                pr += acc[mf][nf][reg] * arv[nf];
            }
#pragma unroll
            for (int off = 1; off < 16; off <<= 1) {
                pl += __shfl_xor(pl, off);
                pr += __shfl_xor(pr, off);
            }
            if (rlo == 0 && r < M) {
                el[(size_t)r * 4 + wid] = pl;
                er[(size_t)r * 4 + wid] = pr;
            }
            if (r < M) {
                us4 o = {f2bf(acc[mf][0][reg]), f2bf(acc[mf][1][reg]),
                         f2bf(acc[mf][2][reg]), f2bf(acc[mf][3][reg])};
                *(us4*)(outb + (size_t)r * 256 + cbase + rlo * 4) = o;  // permuted slots
            }
        }
    }
}

// ---------------- layer-3 fused GEMM: h2(perm) @ [W3 | res_W3] ---------------------------
__global__ __launch_bounds__(256) void gemm_l3(const unsigned short* __restrict__ A,
                                               const unsigned short* __restrict__ Wt,
                                               unsigned short* __restrict__ featb,
                                               float* __restrict__ resf,
                                               const float* __restrict__ al,
                                               const float* __restrict__ ar,
                                               float* __restrict__ el,
                                               float* __restrict__ er, int M) {
    const int K = 256;
    const int lane = threadIdx.x & 63;
    const int wid = threadIdx.x >> 6;
    const int rlo = lane & 15;
    const int q = lane >> 4;
    const int kg = q * 8;
    const int m0 = blockIdx.x * 128 + (wid >> 1) * 64;
    const int ch = wid & 1;
    const int cbase = ch * 64;

    f32x4 acc[4][4];
#pragma unroll
    for (int mf = 0; mf < 4; ++mf)
#pragma unroll
        for (int nf = 0; nf < 4; ++nf) acc[mf][nf] = (f32x4){0.f, 0.f, 0.f, 0.f};

    for (int k0 = 0; k0 < K; k0 += 32) {
        short8 a[4];
#pragma unroll
        for (int mf = 0; mf < 4; ++mf) {
            int r = m0 + mf * 16 + rlo;
            if (r >= M) r = M - 1;
            a[mf] = *(const short8*)(A + (size_t)r * K + k0 + kg);
        }
#pragma unroll
        for (int nf = 0; nf < 4; ++nf) {
            short8 b = *(const short8*)(Wt + (size_t)(cbase + nf * 16 + rlo) * K + k0 + kg);
#pragma unroll
            for (int mf = 0; mf < 4; ++mf)
                acc[mf][nf] = __builtin_amdgcn_mfma_f32_16x16x32_bf16(a[mf], b, acc[mf][nf], 0, 0, 0);
        }
    }

    float alv[4], arv[4];
    if (ch == 0) {
#pragma unroll
        for (int nf = 0; nf < 4; ++nf) {
            alv[nf] = al[nf * 16 + rlo];
            arv[nf] = ar[nf * 16 + rlo];
        }
    }

#pragma unroll
    for (int mf = 0; mf < 4; ++mf) {
#pragma unroll
        for (int reg = 0; reg < 4; ++reg) {
            int r = m0 + mf * 16 + q * 4 + reg;
            if (ch == 0) {
                float pl = 0.f, pr = 0.f;
#pragma unroll
                for (int nf = 0; nf < 4; ++nf) {
                    pl += acc[mf][nf][reg] * alv[nf];
                    pr += acc[mf][nf][reg] * arv[nf];
                }
#pragma unroll
                for (int off = 1; off < 16; off <<= 1) {
                    pl += __shfl_xor(pl, off);
                    pr += __shfl_xor(pr, off);
                }
                if (rlo == 0 && r < M) { el[r] = pl; er[r] = pr; }
                if (r < M) {
                    us4 o = {f2bf(acc[mf][0][reg]), f2bf(acc[mf][1][reg]),
                             f2bf(acc[mf][2][reg]), f2bf(acc[mf][3][reg])};
                    *(us4*)(featb + (size_t)r * 64 + rlo * 4) = o;  // permuted
                }
            } else if (r < M) {
                float4 o = {acc[mf][0][reg], acc[mf][1][reg], acc[mf][2][reg], acc[mf][3][reg]};
                *(float4*)(resf + (size_t)r * 64 + rlo * 4) = o;    // permuted
            }
        }
    }
}

// ---------------- CSR build --------------------------------------------------------------
__global__ void hist_kernel(const int* __restrict__ dst, int* __restrict__ counts, int e) {
    int i = blockIdx.x * blockDim.x + threadIdx.x;
    if (i < e) atomicAdd(&counts[dst[i]], 1);
}

__global__ __launch_bounds__(1024) void scan_block(const int* __restrict__ counts,
                                                   int* __restrict__ offsets,
                                                   int* __restrict__ bsums, int n) {
    __shared__ int ws[16];
    int tid = threadIdx.x, lane = tid & 63, wid = tid >> 6;
    int idx = blockIdx.x * 1024 + tid;
    int v = (idx < n) ? counts[idx] : 0;
    int s = v;
#pragma unroll
    for (int off = 1; off < 64; off <<= 1) {
        int t = __shfl_up(s, off);
        if (lane >= off) s += t;
    }
    if (lane == 63) ws[wid] = s;
    __syncthreads();
    if (tid < 16) {
        int w2 = ws[tid];
#pragma unroll
        for (int off = 1; off < 16; off <<= 1) {
            int t = __shfl_up(w2, off);
            if (tid >= off) w2 += t;
        }
        ws[tid] = w2;
    }
    __syncthreads();
    int wpre = wid ? ws[wid - 1] : 0;
    if (idx < n) offsets[idx] = wpre + s - v;
    if (tid == 0) bsums[blockIdx.x] = ws[15];
}

__global__ __launch_bounds__(1024) void add_off(const int* __restrict__ bsums,
                                                int* __restrict__ offsets,
                                                int* __restrict__ cursor, int n, int e, int nb) {
    __shared__ int base_s;
    int tid = threadIdx.x;
    if (tid < 64) {
        int v = (tid < blockIdx.x && tid < nb) ? bsums[tid] : 0;
#pragma unroll
        for (int off = 32; off > 0; off >>= 1) v += __shfl_xor(v, off);
        if (tid == 0) base_s = v;
    }
    __syncthreads();
    int idx = blockIdx.x * 1024 + tid;
    if (idx < n) {
        int v = offsets[idx] + base_s;
        offsets[idx] = v;
        cursor[idx] = v;
    }
    if (idx == 0) offsets[n] = e;
}

__global__ void scatter_kernel(const int* __restrict__ src, const int* __restrict__ dst,
                               int* __restrict__ cursor, int* __restrict__ csr_src,
                               int* __restrict__ csr_dst, int e) {
    int i = blockIdx.x * blockDim.x + threadIdx.x;
    if (i < e) {
        int d = dst[i];
        int pos = atomicAdd(&cursor[d], 1);
        csr_src[pos] = src[i];
        csr_dst[pos] = d;
    }
}

// ---------------- edge-parallel score precompute (head-major w) --------------------------
// 4 edges per thread. H==4: w[h][e] = exp(min(leaky(el[s][h]+er[d][h]),80)); H==1 flat.
template<int H>
__global__ __launch_bounds__(256) void edge_scores(const int* __restrict__ csr_src,
                                                   const int* __restrict__ csr_dst,
                                                   const float* __restrict__ el,
                                                   const float* __restrict__ er,
                                                   float* __restrict__ w, int E) {
    int e4 = (blockIdx.x * 256 + threadIdx.x) * 4;
    if (e4 >= E) return;
    i32x4 s = *(const i32x4*)(csr_src + e4);
    i32x4 d = *(const i32x4*)(csr_dst + e4);
    if (H == 4) {
        float4 o0, o1, o2, o3;  // per head, 4 edges each
        float* op[4] = {&o0.x, &o1.x, &o2.x, &o3.x};
#pragma unroll
        for (int j = 0; j < 4; ++j) {
            float4 l = *(const float4*)(el + (size_t)s[j] * 4);
            float4 r = *(const float4*)(er + (size_t)d[j] * 4);
            op[0][j] = __expf(fminf(leakyf(l.x + r.x), 80.f));
            op[1][j] = __expf(fminf(leakyf(l.y + r.y), 80.f));
            op[2][j] = __expf(fminf(leakyf(l.z + r.z), 80.f));
            op[3][j] = __expf(fminf(leakyf(l.w + r.w), 80.f));
        }
        *(float4*)(w + 0 * (size_t)E + e4) = o0;
        *(float4*)(w + 1 * (size_t)E + e4) = o1;
        *(float4*)(w + 2 * (size_t)E + e4) = o2;
        *(float4*)(w + 3 * (size_t)E + e4) = o3;
    } else {
        float4 o;
#pragma unroll
        for (int j = 0; j < 4; ++j)
            (&o.x)[j] = __expf(fminf(leakyf(el[s[j]] + er[d[j]]), 80.f));
        *(float4*)(w + e4) = o;
    }
}

// ---------------- aggregate: pure gather + FMA, vectorized index/weight loads ------------
// one wave per node. H==4: lane owns slots [lane*4,+4), head=lane>>4. H==1: lane owns slot lane.
// RES: 0 none, 1 bf16 resid (permuted), 2 f32 resid (permuted). ACT: 0 none, 1 elu.
// FINAL: un-permute on f32 output store.
template<int H, int RES, int ACT, bool OUT_BF16>
__global__ __launch_bounds__(256) void gat_agg(const unsigned short* __restrict__ fp,
                                               const float* __restrict__ wbuf,
                                               const int* __restrict__ offsets,
                                               const int* __restrict__ csr_src,
                                               const void* __restrict__ resid,
                                               void* __restrict__ outv, int n, int E) {
    const int D = H * 64;
    int node = blockIdx.x * 4 + (threadIdx.x >> 6);
    int lane = threadIdx.x & 63;
    if (node >= n) return;
    int e0 = offsets[node], e1 = offsets[node + 1];
    const int hf = (H == 4) ? (lane >> 4) : 0;
    const float* wb = wbuf + (size_t)hf * E;

    float den = 0.f;
    float acc[4] = {0.f, 0.f, 0.f, 0.f};

    for (int e = e0; e < e1; e += 8) {
        i32x4 sv0, sv1;
        f32x4 wv0, wv1;
        __builtin_memcpy(&sv0, csr_src + e, 16);        // unaligned-safe vector loads;
        __builtin_memcpy(&sv1, csr_src + e + 4, 16);    // overreads stay inside d_ws
        __builtin_memcpy(&wv0, wb + e, 16);
        __builtin_memcpy(&wv1, wb + e + 4, 16);
        int s[8];
        float w[8];
#pragma unroll
        for (int j = 0; j < 8; ++j) {
            bool ok = (e + j) < e1;
            int sj = (j < 4) ? sv0[j] : sv1[j - 4];
            float wj = (j < 4) ? wv0[j] : wv1[j - 4];
            s[j] = ok ? sj : 0;
            w[j] = ok ? wj : 0.f;
        }
        if (H == 4) {
            uint2 u[8];
#pragma unroll
            for (int j = 0; j < 8; ++j)
                u[j] = *(const uint2*)(fp + (size_t)s[j] * 256 + lane * 4);
#pragma unroll
            for (int j = 0; j < 8; ++j) {
                den += w[j];
                acc[0] += w[j] * bflo(u[j].x);
                acc[1] += w[j] * bfhi(u[j].x);
                acc[2] += w[j] * bflo(u[j].y);
                acc[3] += w[j] * bfhi(u[j].y);
            }
        } else {
            unsigned u[8];
#pragma unroll
            for (int j = 0; j < 8; ++j)
                u[j] = fp[(size_t)s[j] * 64 + lane];
#pragma unroll
            for (int j = 0; j < 8; ++j) {
                den += w[j];
                acc[0] += w[j] * bflo(u[j]);
            }
        }
    }

    float inv = den > 0.f ? 1.f / den : 0.f;
    float v[4];
#pragma unroll
    for (int i = 0; i < 4; ++i) v[i] = acc[i] * inv;

    if (RES == 1) {
        uint2 ru = *(const uint2*)((const unsigned short*)resid + (size_t)node * D + lane * 4);
        v[0] += bflo(ru.x); v[1] += bfhi(ru.x); v[2] += bflo(ru.y); v[3] += bfhi(ru.y);
    } else if (RES == 2) {
        v[0] += ((const float*)resid)[(size_t)node * D + lane];
    }
    if (ACT == 1) {
#pragma unroll
        for (int i = 0; i < 4; ++i) v[i] = v[i] > 0.f ? v[i] : __expf(v[i]) - 1.f;
    }
    if (OUT_BF16) {
        if (H == 4) {
            us4 o = {f2bf(v[0]), f2bf(v[1]), f2bf(v[2]), f2bf(v[3])};
            *(us4*)((unsigned short*)outv + (size_t)node * D + lane * 4) = o;  // keep permuted
        } else {
            ((unsigned short*)outv)[(size_t)node * D + lane] = f2bf(v[0]);
        }
    } else {
        if (H == 4) {
            float4 o = {v[0], v[1], v[2], v[3]};
            *(float4*)((float*)outv + (size_t)node * D + lane * 4) = o;
        } else {
            // final output: un-permute (slot lane -> true col c64(lane))
            int c = (lane & 3) * 16 + (lane >> 2);
            ((float*)outv)[(size_t)node * D + c] = v[0];
        }
    }
}

// ---------------- launcher ----------------------------------------------------------------
extern "C" void kernel_launch(void* const* d_in, const int* in_sizes, int n_in,
                              void* d_out, int out_size, void* d_ws, size_t ws_size,
                              hipStream_t stream) {
    const float* x      = (const float*)d_in[0];
    const float* W1     = (const float*)d_in[1];
    const float* al1    = (const float*)d_in[2];
    const float* ar1    = (const float*)d_in[3];
    const float* W2     = (const float*)d_in[4];
    const float* al2    = (const float*)d_in[5];
    const float* ar2    = (const float*)d_in[6];
    const float* W3     = (const float*)d_in[7];
    const float* al3    = (const float*)d_in[8];
    const float* ar3    = (const float*)d_in[9];
    const float* res_W3 = (const float*)d_in[10];
    const int*   src    = (const int*)d_in[11];
    const int*   dst    = (const int*)d_in[12];

    const int N = in_sizes[0] / 128;    // 50000
    const int E = in_sizes[11];         // 500000

    float* out = (float*)d_out;

    // workspace layout (16B alignment maintained)
    unsigned short* featb = (unsigned short*)d_ws;          // [N,256] (layer3: [N,64])
    unsigned short* h1    = featb + (size_t)N * 256;        // [N,256]
    unsigned short* h2    = h1 + (size_t)N * 256;           // [N,256]
    unsigned short* W1t   = h2 + (size_t)N * 256;           // [256,128]
    unsigned short* W2t   = W1t + 256 * 128;                // [256,256]
    unsigned short* W3c   = W2t + 256 * 256;                // [128,256] = [W3t | RW3t]
    float* resf = (float*)(W3c + 128 * 256);                // [N,64]
    float* el   = resf + (size_t)N * 64;                    // [N,4]
    float* er   = el + (size_t)N * 4;                       // [N,4]
    float* wbuf = er + (size_t)N * 4;                       // [4][E] head-major
    int* offsets = (int*)(wbuf + (size_t)E * 4);            // [N+1] (padded to N+8)
    int* cursor  = offsets + (N + 8);                       // [N]
    int* csr_src = cursor + N;                              // [E]
    int* csr_dst = csr_src + E;                             // [E]
    int* bsums   = csr_dst + E;                             // [64]

    const int T = 256;
    const int scan_blocks = (N + 1023) / 1024;  // 49 (<= 64 for add_off)
    const int edge_blocks = (E + T - 1) / T;
    const int es_blocks = (E / 4 + T - 1) / T;

    // ---- weight conversions (fused, K-permuted for layers 2/3) ----
    tconv_all<<<512, T, 0, stream>>>(W1, W2, W3, res_W3, W1t, W2t, W3c);

    // ---- CSR by dst ----
    hipMemsetAsync(cursor, 0, (size_t)N * sizeof(int), stream);
    hist_kernel<<<edge_blocks, T, 0, stream>>>(dst, cursor, E);
    scan_block<<<scan_blocks, 1024, 0, stream>>>(cursor, offsets, bsums, N);
    add_off<<<scan_blocks, 1024, 0, stream>>>(bsums, offsets, cursor, N, E, scan_blocks);
    scatter_kernel<<<edge_blocks, T, 0, stream>>>(src, dst, cursor, csr_src, csr_dst, E);

    int gemm12_blocks = (N + 63) / 64;
    int gemm3_blocks = (N + 127) / 128;
    int node_blocks = (N + 3) / 4;

    // ---- Layer 1 ----
    gemm_l12<true><<<gemm12_blocks, T, 0, stream>>>(x, W1t, featb, al1, ar1, el, er, N, 128);
    edge_scores<4><<<es_blocks, T, 0, stream>>>(csr_src, csr_dst, el, er, wbuf, E);
    gat_agg<4, 0, 1, true><<<node_blocks, T, 0, stream>>>(featb, wbuf, offsets, csr_src, nullptr, h1, N, E);

    // ---- Layer 2 ----
    gemm_l12<false><<<gemm12_blocks, T, 0, stream>>>(h1, W2t, featb, al2, ar2, el, er, N, 256);
    edge_scores<4><<<es_blocks, T, 0, stream>>>(csr_src, csr_dst, el, er, wbuf, E);
    gat_agg<4, 1, 1, true><<<node_blocks, T, 0, stream>>>(featb, wbuf, offsets, csr_src, h1, h2, N, E);

    // ---- Layer 3 ----
    gemm_l3<<<gemm3_blocks, T, 0, stream>>>(h2, W3c, featb, resf, al3, ar3, el, er, N);
    edge_scores<1><<<es_blocks, T, 0, stream>>>(csr_src, csr_dst, el, er, wbuf, E);
    gat_agg<1, 2, 0, false><<<node_blocks, T, 0, stream>>>(featb, wbuf, offsets, csr_src, resf, out, N, E);
}

// Round 8
// 286.722 us; speedup vs baseline: 1.0380x; 1.0042x over previous
//
#include <hip/hip_runtime.h>
#include <hip/hip_bf16.h>
#include <math.h>

#define SLOPE 0.2f

typedef __attribute__((ext_vector_type(8))) short short8;
typedef __attribute__((ext_vector_type(4))) float f32x4;
typedef __attribute__((ext_vector_type(4))) int   i32x4;

static __device__ __forceinline__ float leakyf(float x) { return x >= 0.f ? x : SLOPE * x; }
static __device__ __forceinline__ float bflo(unsigned u) { return __builtin_bit_cast(float, u << 16); }
static __device__ __forceinline__ float bfhi(unsigned u) { return __builtin_bit_cast(float, u & 0xffff0000u); }
static __device__ __forceinline__ unsigned short f2bf(float f) {
    unsigned u = __builtin_bit_cast(unsigned, f);
    return (unsigned short)((u + 0x7fff + ((u >> 16) & 1)) >> 16);  // RNE
}

struct __align__(8) us4 { unsigned short a, b, c, d; };

// Permuted within-head column layout: slot p (in [0,64) of a head block) holds true
// column c64(p) = (p&3)*16 + (p>>2).  Inverse: p(c) = (c&15)*4 + (c>>4).

// ---------------- fused weight transpose+convert+K-permute -------------------------------
__global__ __launch_bounds__(256) void tconv_all(const float* __restrict__ W1,
                                                 const float* __restrict__ W2,
                                                 const float* __restrict__ W3,
                                                 const float* __restrict__ rW3,
                                                 unsigned short* __restrict__ W1t,
                                                 unsigned short* __restrict__ W2t,
                                                 unsigned short* __restrict__ W3c) {
    int i = blockIdx.x * 256 + threadIdx.x;
    const float* W; unsigned short* Wt; int K, lNc, idx; bool permK;
    if (i < 32768)       { W = W1;  Wt = W1t;            K = 128; lNc = 8; idx = i;          permK = false; }
    else if (i < 98304)  { W = W2;  Wt = W2t;            K = 256; lNc = 8; idx = i - 32768;  permK = true; }
    else if (i < 114688) { W = W3;  Wt = W3c;            K = 256; lNc = 6; idx = i - 98304;  permK = true; }
    else                 { W = rW3; Wt = W3c + 64 * 256; K = 256; lNc = 6; idx = i - 114688; permK = true; }
    int k = idx >> lNc, n = idx & ((1 << lNc) - 1);
    int kp = permK ? ((k & ~63) | (((k & 15) << 2) | ((k & 63) >> 4))) : k;
    Wt[n * K + kp] = f2bf(W[idx]);
}

// ---------------- MFMA GEMM (layers 1/2) + fused attention projections -------------------
template<bool A_F32>
__global__ __launch_bounds__(256) void gemm_l12(const void* __restrict__ Av,
                                                const unsigned short* __restrict__ Wt,
                                                unsigned short* __restrict__ outb,
                                                const float* __restrict__ al,
                                                const float* __restrict__ ar,
                                                float* __restrict__ el,
                                                float* __restrict__ er,
                                                int M, int K) {
    const int lane = threadIdx.x & 63;
    const int wid = threadIdx.x >> 6;       // head
    const int rlo = lane & 15;
    const int q = lane >> 4;
    const int kg = q * 8;
    const int m0 = blockIdx.x * 64;
    const int cbase = wid * 64;

    f32x4 acc[4][4];
#pragma unroll
    for (int mf = 0; mf < 4; ++mf)
#pragma unroll
        for (int nf = 0; nf < 4; ++nf) acc[mf][nf] = (f32x4){0.f, 0.f, 0.f, 0.f};

    for (int k0 = 0; k0 < K; k0 += 32) {
        short8 a[4];
#pragma unroll
        for (int mf = 0; mf < 4; ++mf) {
            int r = m0 + mf * 16 + rlo;
            if (r >= M) r = M - 1;  // clamp; affects only unstored rows
            if (A_F32) {
                const float* ap = (const float*)Av + (size_t)r * K + k0 + kg;
                float4 f0 = *(const float4*)ap;
                float4 f1 = *(const float4*)(ap + 4);
                short8 t;
                t[0] = f2bf(f0.x); t[1] = f2bf(f0.y); t[2] = f2bf(f0.z); t[3] = f2bf(f0.w);
                t[4] = f2bf(f1.x); t[5] = f2bf(f1.y); t[6] = f2bf(f1.z); t[7] = f2bf(f1.w);
                a[mf] = t;
            } else {
                a[mf] = *(const short8*)((const unsigned short*)Av + (size_t)r * K + k0 + kg);
            }
        }
#pragma unroll
        for (int nf = 0; nf < 4; ++nf) {
            short8 b = *(const short8*)(Wt + (size_t)(cbase + nf * 16 + rlo) * K + k0 + kg);
#pragma unroll
            for (int mf = 0; mf < 4; ++mf)
                acc[mf][nf] = __builtin_amdgcn_mfma_f32_16x16x32_bf16(a[mf], b, acc[mf][nf], 0, 0, 0);
        }
    }

    float alv[4], arv[4];
#pragma unroll
    for (int nf = 0; nf < 4; ++nf) {
        alv[nf] = al[cbase + nf * 16 + rlo];
        arv[nf] = ar[cbase + nf * 16 + rlo];
    }

#pragma unroll
    for (int mf = 0; mf < 4; ++mf) {
#pragma unroll
        for (int reg = 0; reg < 4; ++reg) {
            int r = m0 + mf * 16 + q * 4 + reg;
            float pl = 0.f, pr = 0.f;
#pragma unroll
            for (int nf = 0; nf < 4; ++nf) {
                pl += acc[mf][nf][reg] * alv[nf];
                pr += acc[mf][nf][reg] * arv[nf];
            }
#pragma unroll
            for (int off = 1; off < 16; off <<= 1) {
                pl += __shfl_xor(pl, off);
                pr += __shfl_xor(pr, off);
            }
            if (rlo == 0 && r < M) {
                el[(size_t)r * 4 + wid] = pl;
                er[(size_t)r * 4 + wid] = pr;
            }
            if (r < M) {
                us4 o = {f2bf(acc[mf][0][reg]), f2bf(acc[mf][1][reg]),
                         f2bf(acc[mf][2][reg]), f2bf(acc[mf][3][reg])};
                *(us4*)(outb + (size_t)r * 256 + cbase + rlo * 4) = o;  // permuted slots
            }
        }
    }
}

// ---------------- layer-3 fused GEMM: h2(perm) @ [W3 | res_W3] ---------------------------
__global__ __launch_bounds__(256) void gemm_l3(const unsigned short* __restrict__ A,
                                               const unsigned short* __restrict__ Wt,
                                               unsigned short* __restrict__ featb,
                                               float* __restrict__ resf,
                                               const float* __restrict__ al,
                                               const float* __restrict__ ar,
                                               float* __restrict__ el,
                                               float* __restrict__ er, int M) {
    const int K = 256;
    const int lane = threadIdx.x & 63;
    const int wid = threadIdx.x >> 6;
    const int rlo = lane & 15;
    const int q = lane >> 4;
    const int kg = q * 8;
    const int m0 = blockIdx.x * 128 + (wid >> 1) * 64;
    const int ch = wid & 1;
    const int cbase = ch * 64;

    f32x4 acc[4][4];
#pragma unroll
    for (int mf = 0; mf < 4; ++mf)
#pragma unroll
        for (int nf = 0; nf < 4; ++nf) acc[mf][nf] = (f32x4){0.f, 0.f, 0.f, 0.f};

    for (int k0 = 0; k0 < K; k0 += 32) {
        short8 a[4];
#pragma unroll
        for (int mf = 0; mf < 4; ++mf) {
            int r = m0 + mf * 16 + rlo;
            if (r >= M) r = M - 1;
            a[mf] = *(const short8*)(A + (size_t)r * K + k0 + kg);
        }
#pragma unroll
        for (int nf = 0; nf < 4; ++nf) {
            short8 b = *(const short8*)(Wt + (size_t)(cbase + nf * 16 + rlo) * K + k0 + kg);
#pragma unroll
            for (int mf = 0; mf < 4; ++mf)
                acc[mf][nf] = __builtin_amdgcn_mfma_f32_16x16x32_bf16(a[mf], b, acc[mf][nf], 0, 0, 0);
        }
    }

    float alv[4], arv[4];
    if (ch == 0) {
#pragma unroll
        for (int nf = 0; nf < 4; ++nf) {
            alv[nf] = al[nf * 16 + rlo];
            arv[nf] = ar[nf * 16 + rlo];
        }
    }

#pragma unroll
    for (int mf = 0; mf < 4; ++mf) {
#pragma unroll
        for (int reg = 0; reg < 4; ++reg) {
            int r = m0 + mf * 16 + q * 4 + reg;
            if (ch == 0) {
                float pl = 0.f, pr = 0.f;
#pragma unroll
                for (int nf = 0; nf < 4; ++nf) {
                    pl += acc[mf][nf][reg] * alv[nf];
                    pr += acc[mf][nf][reg] * arv[nf];
                }
#pragma unroll
                for (int off = 1; off < 16; off <<= 1) {
                    pl += __shfl_xor(pl, off);
                    pr += __shfl_xor(pr, off);
                }
                if (rlo == 0 && r < M) { el[r] = pl; er[r] = pr; }
                if (r < M) {
                    us4 o = {f2bf(acc[mf][0][reg]), f2bf(acc[mf][1][reg]),
                             f2bf(acc[mf][2][reg]), f2bf(acc[mf][3][reg])};
                    *(us4*)(featb + (size_t)r * 64 + rlo * 4) = o;  // permuted
                }
            } else if (r < M) {
                float4 o = {acc[mf][0][reg], acc[mf][1][reg], acc[mf][2][reg], acc[mf][3][reg]};
                *(float4*)(resf + (size_t)r * 64 + rlo * 4) = o;    // permuted
            }
        }
    }
}

// ---------------- CSR build --------------------------------------------------------------
__global__ void hist_kernel(const int* __restrict__ dst, int* __restrict__ counts, int e) {
    int i = blockIdx.x * blockDim.x + threadIdx.x;
    if (i < e) atomicAdd(&counts[dst[i]], 1);
}

__global__ __launch_bounds__(1024) void scan_block(const int* __restrict__ counts,
                                                   int* __restrict__ offsets,
                                                   int* __restrict__ bsums, int n) {
    __shared__ int ws[16];
    int tid = threadIdx.x, lane = tid & 63, wid = tid >> 6;
    int idx = blockIdx.x * 1024 + tid;
    int v = (idx < n) ? counts[idx] : 0;
    int s = v;
#pragma unroll
    for (int off = 1; off < 64; off <<= 1) {
        int t = __shfl_up(s, off);
        if (lane >= off) s += t;
    }
    if (lane == 63) ws[wid] = s;
    __syncthreads();
    if (tid < 16) {
        int w2 = ws[tid];
#pragma unroll
        for (int off = 1; off < 16; off <<= 1) {
            int t = __shfl_up(w2, off);
            if (tid >= off) w2 += t;
        }
        ws[tid] = w2;
    }
    __syncthreads();
    int wpre = wid ? ws[wid - 1] : 0;
    if (idx < n) offsets[idx] = wpre + s - v;
    if (tid == 0) bsums[blockIdx.x] = ws[15];
}

__global__ __launch_bounds__(1024) void add_off(const int* __restrict__ bsums,
                                                int* __restrict__ offsets,
                                                int* __restrict__ cursor, int n, int e, int nb) {
    __shared__ int base_s;
    int tid = threadIdx.x;
    if (tid < 64) {
        int v = (tid < blockIdx.x && tid < nb) ? bsums[tid] : 0;
#pragma unroll
        for (int off = 32; off > 0; off >>= 1) v += __shfl_xor(v, off);
        if (tid == 0) base_s = v;
    }
    __syncthreads();
    int idx = blockIdx.x * 1024 + tid;
    if (idx < n) {
        int v = offsets[idx] + base_s;
        offsets[idx] = v;
        cursor[idx] = v;
    }
    if (idx == 0) offsets[n] = e;
}

__global__ void scatter_kernel(const int* __restrict__ src, const int* __restrict__ dst,
                               int* __restrict__ cursor, int* __restrict__ csr_src,
                               int* __restrict__ csr_dst, int e) {
    int i = blockIdx.x * blockDim.x + threadIdx.x;
    if (i < e) {
        int d = dst[i];
        int pos = atomicAdd(&cursor[d], 1);
        csr_src[pos] = src[i];
        csr_dst[pos] = d;
    }
}

// ---------------- edge-parallel score precompute (head-major w) --------------------------
template<int H>
__global__ __launch_bounds__(256) void edge_scores(const int* __restrict__ csr_src,
                                                   const int* __restrict__ csr_dst,
                                                   const float* __restrict__ el,
                                                   const float* __restrict__ er,
                                                   float* __restrict__ w, int E) {
    int e4 = (blockIdx.x * 256 + threadIdx.x) * 4;
    if (e4 >= E) return;
    i32x4 s = *(const i32x4*)(csr_src + e4);
    i32x4 d = *(const i32x4*)(csr_dst + e4);
    if (H == 4) {
        float4 o0, o1, o2, o3;
        float* op[4] = {&o0.x, &o1.x, &o2.x, &o3.x};
#pragma unroll
        for (int j = 0; j < 4; ++j) {
            float4 l = *(const float4*)(el + (size_t)s[j] * 4);
            float4 r = *(const float4*)(er + (size_t)d[j] * 4);
            op[0][j] = __expf(fminf(leakyf(l.x + r.x), 80.f));
            op[1][j] = __expf(fminf(leakyf(l.y + r.y), 80.f));
            op[2][j] = __expf(fminf(leakyf(l.z + r.z), 80.f));
            op[3][j] = __expf(fminf(leakyf(l.w + r.w), 80.f));
        }
        *(float4*)(w + 0 * (size_t)E + e4) = o0;
        *(float4*)(w + 1 * (size_t)E + e4) = o1;
        *(float4*)(w + 2 * (size_t)E + e4) = o2;
        *(float4*)(w + 3 * (size_t)E + e4) = o3;
    } else {
        float4 o;
#pragma unroll
        for (int j = 0; j < 4; ++j)
            (&o.x)[j] = __expf(fminf(leakyf(el[s[j]] + er[d[j]]), 80.f));
        *(float4*)(w + e4) = o;
    }
}

// ---------------- H=4 aggregate: 2 nodes per wave, 16B/lane gathers ----------------------
// half = lane>>5 -> node; sub = lane&31 owns permuted slots [sub*8, sub*8+8) (16B).
// head of sub = sub>>3. RES: 0 none, 1 bf16 resid (permuted). ACT: 1 = elu.
template<int RES, int ACT>
__global__ __launch_bounds__(256) void gat_agg4(const unsigned short* __restrict__ fp,
                                                const float* __restrict__ wbuf,
                                                const int* __restrict__ offsets,
                                                const int* __restrict__ csr_src,
                                                const unsigned short* __restrict__ resid,
                                                unsigned short* __restrict__ outb,
                                                int n, int E) {
    int wv = threadIdx.x >> 6;
    int lane = threadIdx.x & 63;
    int half = lane >> 5;
    int sub = lane & 31;
    int node = blockIdx.x * 8 + wv * 2 + half;

    int e0 = 0, e1 = 0;
    if (node < n) { e0 = offsets[node]; e1 = offsets[node + 1]; }
    int cnt = e1 - e0;
    int ocnt = __shfl_xor(cnt, 32);
    int mc = cnt > ocnt ? cnt : ocnt;

    const float* wb = wbuf + (size_t)(sub >> 3) * E;

    float den = 0.f;
    float acc[8] = {0.f, 0.f, 0.f, 0.f, 0.f, 0.f, 0.f, 0.f};

    for (int t = 0; t < mc; t += 8) {
        i32x4 sv0, sv1;
        f32x4 wv0, wv1;
        __builtin_memcpy(&sv0, csr_src + e0 + t, 16);      // overreads stay inside d_ws
        __builtin_memcpy(&sv1, csr_src + e0 + t + 4, 16);
        __builtin_memcpy(&wv0, wb + e0 + t, 16);
        __builtin_memcpy(&wv1, wb + e0 + t + 4, 16);
        int s[8];
        float w[8];
#pragma unroll
        for (int j = 0; j < 8; ++j) {
            bool ok = (t + j) < cnt;
            int sj = (j < 4) ? sv0[j] : sv1[j - 4];
            float wj = (j < 4) ? wv0[j] : wv1[j - 4];
            s[j] = ok ? sj : 0;
            w[j] = ok ? wj : 0.f;
        }
        uint4 u[8];
#pragma unroll
        for (int j = 0; j < 8; ++j)
            u[j] = *(const uint4*)(fp + (size_t)s[j] * 256 + sub * 8);
#pragma unroll
        for (int j = 0; j < 8; ++j) {
            den += w[j];
            acc[0] += w[j] * bflo(u[j].x);
            acc[1] += w[j] * bfhi(u[j].x);
            acc[2] += w[j] * bflo(u[j].y);
            acc[3] += w[j] * bfhi(u[j].y);
            acc[4] += w[j] * bflo(u[j].z);
            acc[5] += w[j] * bfhi(u[j].z);
            acc[6] += w[j] * bflo(u[j].w);
            acc[7] += w[j] * bfhi(u[j].w);
        }
    }

    if (node >= n) return;

    float inv = den > 0.f ? 1.f / den : 0.f;
    float v[8];
#pragma unroll
    for (int i = 0; i < 8; ++i) v[i] = acc[i] * inv;

    if (RES == 1) {
        uint4 ru = *(const uint4*)(resid + (size_t)node * 256 + sub * 8);
        v[0] += bflo(ru.x); v[1] += bfhi(ru.x);
        v[2] += bflo(ru.y); v[3] += bfhi(ru.y);
        v[4] += bflo(ru.z); v[5] += bfhi(ru.z);
        v[6] += bflo(ru.w); v[7] += bfhi(ru.w);
    }
    if (ACT == 1) {
#pragma unroll
        for (int i = 0; i < 8; ++i) v[i] = v[i] > 0.f ? v[i] : __expf(v[i]) - 1.f;
    }
    uint4 o;
    o.x = (unsigned)f2bf(v[0]) | ((unsigned)f2bf(v[1]) << 16);
    o.y = (unsigned)f2bf(v[2]) | ((unsigned)f2bf(v[3]) << 16);
    o.z = (unsigned)f2bf(v[4]) | ((unsigned)f2bf(v[5]) << 16);
    o.w = (unsigned)f2bf(v[6]) | ((unsigned)f2bf(v[7]) << 16);
    *(uint4*)(outb + (size_t)node * 256 + sub * 8) = o;
}

// ---------------- H=1 aggregate: 4 nodes per wave, 8B/lane gathers -----------------------
// quarter = lane>>4 -> node; sub = lane&15 owns permuted slots [sub*4,+4).
// resid f32 permuted; output f32 true layout (un-permute).
__global__ __launch_bounds__(256) void gat_agg1(const unsigned short* __restrict__ fp,
                                                const float* __restrict__ wbuf,
                                                const int* __restrict__ offsets,
                                                const int* __restrict__ csr_src,
                                                const float* __restrict__ resf,
                                                float* __restrict__ outv, int n, int E) {
    int wv = threadIdx.x >> 6;
    int lane = threadIdx.x & 63;
    int sub = lane & 15;
    int node = blockIdx.x * 16 + wv * 4 + (lane >> 4);

    int e0 = 0, e1 = 0;
    if (node < n) { e0 = offsets[node]; e1 = offsets[node + 1]; }
    int cnt = e1 - e0;
    int m1 = __shfl_xor(cnt, 16);
    int mc = cnt > m1 ? cnt : m1;
    int m2 = __shfl_xor(mc, 32);
    mc = mc > m2 ? mc : m2;

    float den = 0.f;
    float acc[4] = {0.f, 0.f, 0.f, 0.f};

    for (int t = 0; t < mc; t += 8) {
        i32x4 sv0, sv1;
        f32x4 wv0, wv1;
        __builtin_memcpy(&sv0, csr_src + e0 + t, 16);
        __builtin_memcpy(&sv1, csr_src + e0 + t + 4, 16);
        __builtin_memcpy(&wv0, wbuf + e0 + t, 16);
        __builtin_memcpy(&wv1, wbuf + e0 + t + 4, 16);
        int s[8];
        float w[8];
#pragma unroll
        for (int j = 0; j < 8; ++j) {
            bool ok = (t + j) < cnt;
            int sj = (j < 4) ? sv0[j] : sv1[j - 4];
            float wj = (j < 4) ? wv0[j] : wv1[j - 4];
            s[j] = ok ? sj : 0;
            w[j] = ok ? wj : 0.f;
        }
        uint2 u[8];
#pragma unroll
        for (int j = 0; j < 8; ++j)
            u[j] = *(const uint2*)(fp + (size_t)s[j] * 64 + sub * 4);
#pragma unroll
        for (int j = 0; j < 8; ++j) {
            den += w[j];
            acc[0] += w[j] * bflo(u[j].x);
            acc[1] += w[j] * bfhi(u[j].x);
            acc[2] += w[j] * bflo(u[j].y);
            acc[3] += w[j] * bfhi(u[j].y);
        }
    }

    if (node >= n) return;

    float inv = den > 0.f ? 1.f / den : 0.f;
    float4 rv = *(const float4*)(resf + (size_t)node * 64 + sub * 4);
    float v[4];
    v[0] = acc[0] * inv + rv.x;
    v[1] = acc[1] * inv + rv.y;
    v[2] = acc[2] * inv + rv.z;
    v[3] = acc[3] * inv + rv.w;

#pragma unroll
    for (int i = 0; i < 4; ++i) {
        int p = sub * 4 + i;                 // permuted slot
        int c = (p & 3) * 16 + (p >> 2);     // true column
        outv[(size_t)node * 64 + c] = v[i];
    }
}

// ---------------- launcher ----------------------------------------------------------------
extern "C" void kernel_launch(void* const* d_in, const int* in_sizes, int n_in,
                              void* d_out, int out_size, void* d_ws, size_t ws_size,
                              hipStream_t stream) {
    const float* x      = (const float*)d_in[0];
    const float* W1     = (const float*)d_in[1];
    const float* al1    = (const float*)d_in[2];
    const float* ar1    = (const float*)d_in[3];
    const float* W2     = (const float*)d_in[4];
    const float* al2    = (const float*)d_in[5];
    const float* ar2    = (const float*)d_in[6];
    const float* W3     = (const float*)d_in[7];
    const float* al3    = (const float*)d_in[8];
    const float* ar3    = (const float*)d_in[9];
    const float* res_W3 = (const float*)d_in[10];
    const int*   src    = (const int*)d_in[11];
    const int*   dst    = (const int*)d_in[12];

    const int N = in_sizes[0] / 128;    // 50000
    const int E = in_sizes[11];         // 500000

    float* out = (float*)d_out;

    // workspace layout (16B alignment maintained)
    unsigned short* featb = (unsigned short*)d_ws;          // [N,256] (layer3: [N,64])
    unsigned short* h1    = featb + (size_t)N * 256;        // [N,256]
    unsigned short* h2    = h1 + (size_t)N * 256;           // [N,256]
    unsigned short* W1t   = h2 + (size_t)N * 256;           // [256,128]
    unsigned short* W2t   = W1t + 256 * 128;                // [256,256]
    unsigned short* W3c   = W2t + 256 * 256;                // [128,256] = [W3t | RW3t]
    float* resf = (float*)(W3c + 128 * 256);                // [N,64]
    float* el   = resf + (size_t)N * 64;                    // [N,4]
    float* er   = el + (size_t)N * 4;                       // [N,4]
    float* wbuf = er + (size_t)N * 4;                       // [4][E] head-major
    int* offsets = (int*)(wbuf + (size_t)E * 4);            // [N+1] (padded)
    int* cursor  = offsets + (N + 8);                       // [N]
    int* csr_src = cursor + N;                              // [E]
    int* csr_dst = csr_src + E;                             // [E]
    int* bsums   = csr_dst + E;                             // [64]

    const int T = 256;
    const int scan_blocks = (N + 1023) / 1024;  // 49 (<= 64 for add_off)
    const int edge_blocks = (E + T - 1) / T;
    const int es_blocks = (E / 4 + T - 1) / T;

    // ---- weight conversions (fused, K-permuted for layers 2/3) ----
    tconv_all<<<512, T, 0, stream>>>(W1, W2, W3, res_W3, W1t, W2t, W3c);

    // ---- CSR by dst ----
    hipMemsetAsync(cursor, 0, (size_t)N * sizeof(int), stream);
    hist_kernel<<<edge_blocks, T, 0, stream>>>(dst, cursor, E);
    scan_block<<<scan_blocks, 1024, 0, stream>>>(cursor, offsets, bsums, N);
    add_off<<<scan_blocks, 1024, 0, stream>>>(bsums, offsets, cursor, N, E, scan_blocks);
    scatter_kernel<<<edge_blocks, T, 0, stream>>>(src, dst, cursor, csr_src, csr_dst, E);

    int gemm12_blocks = (N + 63) / 64;
    int gemm3_blocks = (N + 127) / 128;
    int agg4_blocks = (N + 7) / 8;
    int agg1_blocks = (N + 15) / 16;

    // ---- Layer 1 ----
    gemm_l12<true><<<gemm12_blocks, T, 0, stream>>>(x, W1t, featb, al1, ar1, el, er, N, 128);
    edge_scores<4><<<es_blocks, T, 0, stream>>>(csr_src, csr_dst, el, er, wbuf, E);
    gat_agg4<0, 1><<<agg4_blocks, T, 0, stream>>>(featb, wbuf, offsets, csr_src, nullptr, h1, N, E);

    // ---- Layer 2 ----
    gemm_l12<false><<<gemm12_blocks, T, 0, stream>>>(h1, W2t, featb, al2, ar2, el, er, N, 256);
    edge_scores<4><<<es_blocks, T, 0, stream>>>(csr_src, csr_dst, el, er, wbuf, E);
    gat_agg4<1, 1><<<agg4_blocks, T, 0, stream>>>(featb, wbuf, offsets, csr_src, h1, h2, N, E);

    // ---- Layer 3 ----
    gemm_l3<<<gemm3_blocks, T, 0, stream>>>(h2, W3c, featb, resf, al3, ar3, el, er, N);
    edge_scores<1><<<es_blocks, T, 0, stream>>>(csr_src, csr_dst, el, er, wbuf, E);
    gat_agg1<<<agg1_blocks, T, 0, stream>>>(featb, wbuf, offsets, csr_src, resf, out, N, E);
}